// Round 1
// baseline (725.291 us; speedup 1.0000x reference)
//
#include <hip/hip_runtime.h>
#include <hip/hip_bf16.h>

// LinearAttention: B=4, T=8192, E=1024, H=16, D=64
// out = ((relu(hq)+eps) einsum stuff) @ Wo^T + bo   -- see reference.
//
// Pipeline:
//  1. cast_weights: Wq/Wk/Wv/Wo fp32 -> bf16 in ws
//  2. gemm_proj x3: X @ W^T + b (+feature map for Q,K) -> Qp/Kp/Vp (bf16)
//  3. kv_partial:   per (b,h,split): partial KV[d][e], Ksum[d] (fp32)
//  4. kv_reduce:    sum partials -> KVt[bh][80][64] bf16 (row 64 = Ksum, 65..79 = 0)
//  5. attn:         per (b,h,256 rows): MFMA Q@KV and Q@Ksum (as col 64..79),
//                   divide, write att in-place over Qp
//  6. gemm_out:     att @ Wo^T + bo -> d_out (fp32)
//
// Workspace: 8MB weights + 192MB Qp/Kp/Vp + 640KB KVt + 16MB KVpart + 256KB Ksum
//            ~= 217MB total.

#define T_ 8192
#define E_ 1024
#define M_ 32768
#define SCALE_ 0.125f
#define EPS_FM_ 1e-6f
#define EPS_Z_ 1e-8f

typedef __bf16 bf16;
typedef __attribute__((ext_vector_type(8))) __bf16 bf16x8;
typedef __attribute__((ext_vector_type(4))) float f32x4;

__device__ __forceinline__ void gl_lds16(const void* g, void* l) {
  __builtin_amdgcn_global_load_lds(
      (const __attribute__((address_space(1))) void*)g,
      (__attribute__((address_space(3))) void*)l, 16, 0, 0);
}

__global__ __launch_bounds__(256) void cast_weights(
    const float* __restrict__ Wq, const float* __restrict__ Wk,
    const float* __restrict__ Wv, const float* __restrict__ Wo,
    bf16* __restrict__ out) {
  int which = blockIdx.y;
  int j = (blockIdx.x * 256 + threadIdx.x) * 4;
  const float* s = (which == 0) ? Wq : (which == 1) ? Wk : (which == 2) ? Wv : Wo;
  float4 v = *(const float4*)(s + j);
  bf16* o = out + (size_t)which * (1u << 20) + j;
  o[0] = (bf16)v.x; o[1] = (bf16)v.y; o[2] = (bf16)v.z; o[3] = (bf16)v.w;
}

// ---- projection GEMM: P = f(X @ W^T + b), X fp32 (M x 1024), W bf16 (1024x1024)
__global__ __launch_bounds__(256) void gemm_proj(
    const float* __restrict__ X, const bf16* __restrict__ W,
    const float* __restrict__ bias, bf16* __restrict__ P, int mode) {
  __shared__ __align__(16) bf16 Al[128 * 32];
  __shared__ __align__(16) bf16 Bl[128 * 32];
  const int tid = threadIdx.x;
  const int m0 = blockIdx.x * 128;
  const int n0 = blockIdx.y * 128;
  const int wave = tid >> 6, lane = tid & 63;
  const int wm = wave >> 1, wn = wave & 1;
  const int l16 = lane & 15, kg = lane >> 4;

  f32x4 acc[4][4] = {};
  const int ar = tid >> 1;
  const int ak = (tid & 1) << 4;
  const float* asrc = X + (size_t)(m0 + ar) * 1024 + ak;

  for (int kt = 0; kt < 32; ++kt) {
    __syncthreads();
    {  // stage A: fp32 -> bf16 -> LDS
      const float* s = asrc + kt * 32;
      float4 v0 = *(const float4*)(s + 0);
      float4 v1 = *(const float4*)(s + 4);
      float4 v2 = *(const float4*)(s + 8);
      float4 v3 = *(const float4*)(s + 12);
      bf16x8 p0 = {(bf16)v0.x, (bf16)v0.y, (bf16)v0.z, (bf16)v0.w,
                   (bf16)v1.x, (bf16)v1.y, (bf16)v1.z, (bf16)v1.w};
      bf16x8 p1 = {(bf16)v2.x, (bf16)v2.y, (bf16)v2.z, (bf16)v2.w,
                   (bf16)v3.x, (bf16)v3.y, (bf16)v3.z, (bf16)v3.w};
      *(bf16x8*)&Al[ar * 32 + ak] = p0;
      *(bf16x8*)&Al[ar * 32 + ak + 8] = p1;
    }
#pragma unroll
    for (int i = 0; i < 2; ++i) {  // stage B via global_load_lds (linear)
      int e8 = tid + i * 256;
      const bf16* s = W + (size_t)(n0 + (e8 >> 2)) * 1024 + kt * 32 + (e8 & 3) * 8;
      gl_lds16(s, &Bl[e8 * 8]);
    }
    __syncthreads();
    bf16x8 a[4], bfr[4];
#pragma unroll
    for (int f = 0; f < 4; ++f)
      a[f] = *(const bf16x8*)&Al[(wm * 64 + f * 16 + l16) * 32 + kg * 8];
#pragma unroll
    for (int f = 0; f < 4; ++f)
      bfr[f] = *(const bf16x8*)&Bl[(wn * 64 + f * 16 + l16) * 32 + kg * 8];
#pragma unroll
    for (int fm = 0; fm < 4; ++fm)
#pragma unroll
      for (int fn = 0; fn < 4; ++fn)
        acc[fm][fn] = __builtin_amdgcn_mfma_f32_16x16x32_bf16(
            a[fm], bfr[fn], acc[fm][fn], 0, 0, 0);
  }
#pragma unroll
  for (int fn = 0; fn < 4; ++fn) {
    int col = n0 + wn * 64 + fn * 16 + l16;
    float bv = bias[col];
#pragma unroll
    for (int fm = 0; fm < 4; ++fm) {
      int row = m0 + wm * 64 + fm * 16 + kg * 4;
#pragma unroll
      for (int i = 0; i < 4; ++i) {
        float v = acc[fm][fn][i] + bv;
        if (mode < 2) { v *= SCALE_; v = fmaxf(v, 0.f) + EPS_FM_; }
        P[(size_t)(row + i) * 1024 + col] = (bf16)v;
      }
    }
  }
}

// ---- output GEMM: Out = A @ W^T + b, A bf16, out fp32
__global__ __launch_bounds__(256) void gemm_out(
    const bf16* __restrict__ A, const bf16* __restrict__ W,
    const float* __restrict__ bias, float* __restrict__ Out) {
  __shared__ __align__(16) bf16 Al[128 * 32];
  __shared__ __align__(16) bf16 Bl[128 * 32];
  const int tid = threadIdx.x;
  const int m0 = blockIdx.x * 128;
  const int n0 = blockIdx.y * 128;
  const int wave = tid >> 6, lane = tid & 63;
  const int wm = wave >> 1, wn = wave & 1;
  const int l16 = lane & 15, kg = lane >> 4;

  f32x4 acc[4][4] = {};
  for (int kt = 0; kt < 32; ++kt) {
    __syncthreads();
#pragma unroll
    for (int i = 0; i < 2; ++i) {
      int e8 = tid + i * 256;
      const bf16* sa = A + (size_t)(m0 + (e8 >> 2)) * 1024 + kt * 32 + (e8 & 3) * 8;
      gl_lds16(sa, &Al[e8 * 8]);
      const bf16* sb = W + (size_t)(n0 + (e8 >> 2)) * 1024 + kt * 32 + (e8 & 3) * 8;
      gl_lds16(sb, &Bl[e8 * 8]);
    }
    __syncthreads();
    bf16x8 a[4], bfr[4];
#pragma unroll
    for (int f = 0; f < 4; ++f)
      a[f] = *(const bf16x8*)&Al[(wm * 64 + f * 16 + l16) * 32 + kg * 8];
#pragma unroll
    for (int f = 0; f < 4; ++f)
      bfr[f] = *(const bf16x8*)&Bl[(wn * 64 + f * 16 + l16) * 32 + kg * 8];
#pragma unroll
    for (int fm = 0; fm < 4; ++fm)
#pragma unroll
      for (int fn = 0; fn < 4; ++fn)
        acc[fm][fn] = __builtin_amdgcn_mfma_f32_16x16x32_bf16(
            a[fm], bfr[fn], acc[fm][fn], 0, 0, 0);
  }
#pragma unroll
  for (int fn = 0; fn < 4; ++fn) {
    int col = n0 + wn * 64 + fn * 16 + l16;
    float bv = bias[col];
#pragma unroll
    for (int fm = 0; fm < 4; ++fm) {
      int row = m0 + wm * 64 + fm * 16 + kg * 4;
#pragma unroll
      for (int i = 0; i < 4; ++i)
        Out[(size_t)(row + i) * 1024 + col] = acc[fm][fn][i] + bv;
    }
  }
}

// ---- KV partial: per (bh, split): KV[d][e] += K[t,d]*V[t,e], Ksum[d] += K[t,d]
__global__ __launch_bounds__(256) void kv_partial(
    const bf16* __restrict__ Kp, const bf16* __restrict__ Vp,
    float* __restrict__ KVpart, float* __restrict__ KsumPart) {
  __shared__ __align__(16) float Kl[64 * 64];
  __shared__ __align__(16) float Vl[64 * 64];
  const int bh = blockIdx.x, split = blockIdx.y;
  const int b = bh >> 4, h = bh & 15;
  const int tid = threadIdx.x;
  const int d0 = (tid >> 4) * 4, e0 = (tid & 15) * 4;
  float acc[4][4] = {};
  float ks[4] = {};
  const int sr = tid >> 2, sc = (tid & 3) * 16;
  for (int tc = 0; tc < 8; ++tc) {
    int t0 = split * 512 + tc * 64;
    __syncthreads();
    {
      size_t base = (size_t)(b * 8192 + t0 + sr) * 1024 + h * 64 + sc;
      bf16x8 k0 = *(const bf16x8*)(Kp + base);
      bf16x8 k1 = *(const bf16x8*)(Kp + base + 8);
      bf16x8 v0 = *(const bf16x8*)(Vp + base);
      bf16x8 v1 = *(const bf16x8*)(Vp + base + 8);
#pragma unroll
      for (int j = 0; j < 8; ++j) {
        Kl[sr * 64 + sc + j] = (float)k0[j];
        Kl[sr * 64 + sc + 8 + j] = (float)k1[j];
        Vl[sr * 64 + sc + j] = (float)v0[j];
        Vl[sr * 64 + sc + 8 + j] = (float)v1[j];
      }
    }
    __syncthreads();
#pragma unroll 4
    for (int t = 0; t < 64; ++t) {
      f32x4 kv = *(const f32x4*)&Kl[t * 64 + d0];
      f32x4 vv = *(const f32x4*)&Vl[t * 64 + e0];
#pragma unroll
      for (int i = 0; i < 4; ++i) {
#pragma unroll
        for (int j = 0; j < 4; ++j) acc[i][j] += kv[i] * vv[j];
        ks[i] += kv[i];
      }
    }
  }
  float* outp = KVpart + ((size_t)split * 64 + bh) * 4096;
#pragma unroll
  for (int i = 0; i < 4; ++i)
#pragma unroll
    for (int j = 0; j < 4; ++j) outp[(d0 + i) * 64 + e0 + j] = acc[i][j];
  if ((tid & 15) == 0) {
    float* kp = KsumPart + ((size_t)split * 64 + bh) * 64;
#pragma unroll
    for (int i = 0; i < 4; ++i) kp[d0 + i] = ks[i];
  }
}

// ---- reduce partials -> KVt[bh][80][64] bf16 (transposed [e][d]; row64=Ksum, 65..79=0)
__global__ __launch_bounds__(256) void kv_reduce(
    const float* __restrict__ KVpart, const float* __restrict__ KsumPart,
    bf16* __restrict__ KVt) {
  int bh = blockIdx.x;
  for (int idx = threadIdx.x; idx < 5120; idx += 256) {
    float s = 0.f;
    if (idx < 4096) {
      int e = idx >> 6, d = idx & 63;
      for (int sp = 0; sp < 16; ++sp)
        s += KVpart[((size_t)sp * 64 + bh) * 4096 + d * 64 + e];
    } else if (idx < 4160) {
      int d = idx - 4096;
      for (int sp = 0; sp < 16; ++sp)
        s += KsumPart[((size_t)sp * 64 + bh) * 64 + d];
    }
    KVt[(size_t)bh * 5120 + idx] = (bf16)s;
  }
}

// ---- attention: out = (Q @ KV) / (Q . Ksum + eps), written in-place over Qp
__global__ __launch_bounds__(256) void attn(
    const bf16* __restrict__ KVt, bf16* __restrict__ QA) {
  __shared__ __align__(16) bf16 Bt[5120];
  const int bh = blockIdx.x, tc = blockIdx.y;
  const int b = bh >> 4, h = bh & 15;
  const int tid = threadIdx.x;
  const int m0 = b * 8192 + tc * 256;
#pragma unroll
  for (int i = 0; i < 3; ++i) {
    int e8 = tid + i * 256;
    if (e8 < 640) gl_lds16(KVt + (size_t)bh * 5120 + e8 * 8, &Bt[e8 * 8]);
  }
  const int wave = tid >> 6, lane = tid & 63;
  const int l16 = lane & 15, kg = lane >> 4;
  const int rowbase = m0 + wave * 64;
  __syncthreads();
  bf16x8 a[4][2];
#pragma unroll
  for (int fm = 0; fm < 4; ++fm)
#pragma unroll
    for (int kk = 0; kk < 2; ++kk)
      a[fm][kk] = *(const bf16x8*)(QA + (size_t)(rowbase + fm * 16 + l16) * 1024 +
                                   h * 64 + kk * 32 + kg * 8);
  f32x4 acc[4][4] = {};
  f32x4 accz[4] = {};
#pragma unroll
  for (int kk = 0; kk < 2; ++kk) {
    bf16x8 bz = *(const bf16x8*)&Bt[(64 + l16) * 64 + kk * 32 + kg * 8];
#pragma unroll
    for (int fn = 0; fn < 4; ++fn) {
      bf16x8 bb = *(const bf16x8*)&Bt[(fn * 16 + l16) * 64 + kk * 32 + kg * 8];
#pragma unroll
      for (int fm = 0; fm < 4; ++fm)
        acc[fm][fn] = __builtin_amdgcn_mfma_f32_16x16x32_bf16(
            a[fm][kk], bb, acc[fm][fn], 0, 0, 0);
    }
#pragma unroll
    for (int fm = 0; fm < 4; ++fm)
      accz[fm] = __builtin_amdgcn_mfma_f32_16x16x32_bf16(
          a[fm][kk], bz, accz[fm], 0, 0, 0);
  }
#pragma unroll
  for (int fm = 0; fm < 4; ++fm) {
#pragma unroll
    for (int i = 0; i < 4; ++i) {
      float z = __shfl(accz[fm][i], (lane & 48), 64) + EPS_Z_;
      float rz = 1.0f / z;
      int row = rowbase + fm * 16 + kg * 4 + i;
#pragma unroll
      for (int fn = 0; fn < 4; ++fn)
        QA[(size_t)row * 1024 + h * 64 + fn * 16 + l16] =
            (bf16)(acc[fm][fn][i] * rz);
    }
  }
}

extern "C" void kernel_launch(void* const* d_in, const int* in_sizes, int n_in,
                              void* d_out, int out_size, void* d_ws, size_t ws_size,
                              hipStream_t stream) {
  const float* query = (const float*)d_in[0];
  const float* key = (const float*)d_in[1];
  const float* value = (const float*)d_in[2];
  const float* Wq = (const float*)d_in[3];
  const float* bq = (const float*)d_in[4];
  const float* Wk = (const float*)d_in[5];
  const float* bk = (const float*)d_in[6];
  const float* Wv = (const float*)d_in[7];
  const float* bv = (const float*)d_in[8];
  const float* Wo = (const float*)d_in[9];
  const float* bo = (const float*)d_in[10];
  float* out = (float*)d_out;

  bf16* ws = (bf16*)d_ws;
  bf16* Wqb = ws;
  bf16* Wkb = ws + (1u << 20);
  bf16* Wvb = ws + (2u << 20);
  bf16* Wob = ws + (3u << 20);
  bf16* Qp = ws + (4u << 20);
  bf16* Kp = Qp + 33554432u;
  bf16* Vp = Kp + 33554432u;
  bf16* KVt = Vp + 33554432u;
  float* KVpart = (float*)(KVt + 327680u);
  float* KsumPart = KVpart + 16 * 64 * 4096;

  cast_weights<<<dim3(1024, 4), 256, 0, stream>>>(Wq, Wk, Wv, Wo, Wqb);
  dim3 gg(256, 8);
  gemm_proj<<<gg, 256, 0, stream>>>(query, Wqb, bq, Qp, 0);
  gemm_proj<<<gg, 256, 0, stream>>>(key, Wkb, bk, Kp, 1);
  gemm_proj<<<gg, 256, 0, stream>>>(value, Wvb, bv, Vp, 2);
  kv_partial<<<dim3(64, 16), 256, 0, stream>>>(Kp, Vp, KVpart, KsumPart);
  kv_reduce<<<64, 256, 0, stream>>>(KVpart, KsumPart, KVt);
  attn<<<dim3(64, 32), 256, 0, stream>>>(KVt, Qp);
  gemm_out<<<gg, 256, 0, stream>>>(Qp, Wob, bo, out);
}

// Round 2
// 612.674 us; speedup vs baseline: 1.1838x; 1.1838x over previous
//
#include <hip/hip_runtime.h>
#include <hip/hip_bf16.h>

// LinearAttention: B=4, T=8192, E=1024, H=16, D=64
//
// Pipeline (all GEMMs pure-bf16 m97-structure, global_load_lds both operands):
//  1. cast_f2b: weights fp32->bf16 (ws), and per-input q/k/v fp32->bf16 into
//     Xc which lives in d_out (scratch until final GEMM writes it).
//  2. gemm_bt<0/1>: P = f(Xc @ W^T + b) -> Qp/Kp/Vp bf16
//  3. kv_partial / kv_reduce: KVt[bh][80][64] bf16 ([e][d] transposed; row 64=Ksum)
//  4. attn: (Q@KV)/(Q.Ksum+eps) in-place over Qp
//  5. gemm_bt<2>: att @ Wo^T + bo -> d_out fp32
//
// Workspace: 8MB weights + 192MB Qp/Kp/Vp + 640KB KVt + 16MB KVpart + 256KB Ksum

#define SCALE_ 0.125f
#define EPS_FM_ 1e-6f
#define EPS_Z_ 1e-8f

typedef __bf16 bf16;
typedef __attribute__((ext_vector_type(4))) __bf16 bf16x4;
typedef __attribute__((ext_vector_type(8))) __bf16 bf16x8;
typedef __attribute__((ext_vector_type(4))) float f32x4;

__device__ __forceinline__ void gl_lds16(const void* g, void* l) {
  __builtin_amdgcn_global_load_lds(
      (const __attribute__((address_space(1))) void*)g,
      (__attribute__((address_space(3))) void*)l, 16, 0, 0);
}

// ---- fp32 -> bf16 cast, grid-stride, vectorized 16B in / 8B out
__global__ __launch_bounds__(256) void cast_f2b(const float* __restrict__ s,
                                                bf16* __restrict__ o, int n) {
  const int stride = gridDim.x * 256 * 4;
  for (int j = (blockIdx.x * 256 + threadIdx.x) * 4; j < n; j += stride) {
    float4 v = *(const float4*)(s + j);
    bf16x4 p = {(bf16)v.x, (bf16)v.y, (bf16)v.z, (bf16)v.w};
    *(bf16x4*)(o + j) = p;
  }
}

// ---- GEMM: Out = f(A @ W^T + bias); A bf16 [M][1024], W bf16 [N][1024]
// OM 0: featuremap -> bf16; OM 1: plain -> bf16; OM 2: plain -> fp32
// 128x128 tile, BK=32, 4 waves, global_load_lds both operands, XCD swizzle.
template <int OM>
__global__ __launch_bounds__(256) void gemm_bt(
    const bf16* __restrict__ A, const bf16* __restrict__ W,
    const float* __restrict__ bias, bf16* __restrict__ Pb,
    float* __restrict__ Pf) {
  __shared__ __align__(16) bf16 Al[128 * 32];
  __shared__ __align__(16) bf16 Bl[128 * 32];
  const int tid = threadIdx.x;
  // bijective XCD swizzle (gridDim.x % 8 == 0): each XCD gets a contiguous
  // chunk; within a chunk n-tile is fastest -> A-panel shared by 8
  // consecutive blocks, 8 B-panels (2MB) stay L2-resident.
  const int bid = blockIdx.x;
  const int wg = (bid & 7) * (gridDim.x >> 3) + (bid >> 3);
  const int m0 = (wg >> 3) * 128;
  const int n0 = (wg & 7) * 128;
  const int wave = tid >> 6, lane = tid & 63;
  const int wm = wave >> 1, wn = wave & 1;
  const int l16 = lane & 15, kg = lane >> 4;

  f32x4 acc[4][4] = {};
  for (int kt = 0; kt < 32; ++kt) {
    __syncthreads();
#pragma unroll
    for (int i = 0; i < 2; ++i) {
      const int e8 = tid + i * 256;
      const bf16* sa = A + (size_t)(m0 + (e8 >> 2)) * 1024 + kt * 32 + (e8 & 3) * 8;
      gl_lds16(sa, &Al[e8 * 8]);
      const bf16* sb = W + (size_t)(n0 + (e8 >> 2)) * 1024 + kt * 32 + (e8 & 3) * 8;
      gl_lds16(sb, &Bl[e8 * 8]);
    }
    __syncthreads();
    bf16x8 a[4], bfr[4];
#pragma unroll
    for (int f = 0; f < 4; ++f)
      a[f] = *(const bf16x8*)&Al[(wm * 64 + f * 16 + l16) * 32 + kg * 8];
#pragma unroll
    for (int f = 0; f < 4; ++f)
      bfr[f] = *(const bf16x8*)&Bl[(wn * 64 + f * 16 + l16) * 32 + kg * 8];
#pragma unroll
    for (int fm = 0; fm < 4; ++fm)
#pragma unroll
      for (int fn = 0; fn < 4; ++fn)
        acc[fm][fn] = __builtin_amdgcn_mfma_f32_16x16x32_bf16(
            a[fm], bfr[fn], acc[fm][fn], 0, 0, 0);
  }
#pragma unroll
  for (int fn = 0; fn < 4; ++fn) {
    const int col = n0 + wn * 64 + fn * 16 + l16;
    const float bv = bias[col];
#pragma unroll
    for (int fm = 0; fm < 4; ++fm) {
      const int row = m0 + wm * 64 + fm * 16 + kg * 4;
#pragma unroll
      for (int i = 0; i < 4; ++i) {
        float v = acc[fm][fn][i] + bv;
        if (OM == 0) { v *= SCALE_; v = fmaxf(v, 0.f) + EPS_FM_; }
        if (OM < 2)
          Pb[(size_t)(row + i) * 1024 + col] = (bf16)v;
        else
          Pf[(size_t)(row + i) * 1024 + col] = v;
      }
    }
  }
}

// ---- KV partial: per (bh, split): KV[d][e] += K[t,d]*V[t,e], Ksum[d] += K[t,d]
__global__ __launch_bounds__(256) void kv_partial(
    const bf16* __restrict__ Kp, const bf16* __restrict__ Vp,
    float* __restrict__ KVpart, float* __restrict__ KsumPart) {
  __shared__ __align__(16) float Kl[64 * 64];
  __shared__ __align__(16) float Vl[64 * 64];
  const int bh = blockIdx.x, split = blockIdx.y;
  const int b = bh >> 4, h = bh & 15;
  const int tid = threadIdx.x;
  const int d0 = (tid >> 4) * 4, e0 = (tid & 15) * 4;
  float acc[4][4] = {};
  float ks[4] = {};
  const int sr = tid >> 2, sc = (tid & 3) * 16;
  for (int tc = 0; tc < 8; ++tc) {
    int t0 = split * 512 + tc * 64;
    __syncthreads();
    {
      size_t base = (size_t)(b * 8192 + t0 + sr) * 1024 + h * 64 + sc;
      bf16x8 k0 = *(const bf16x8*)(Kp + base);
      bf16x8 k1 = *(const bf16x8*)(Kp + base + 8);
      bf16x8 v0 = *(const bf16x8*)(Vp + base);
      bf16x8 v1 = *(const bf16x8*)(Vp + base + 8);
#pragma unroll
      for (int j = 0; j < 8; ++j) {
        Kl[sr * 64 + sc + j] = (float)k0[j];
        Kl[sr * 64 + sc + 8 + j] = (float)k1[j];
        Vl[sr * 64 + sc + j] = (float)v0[j];
        Vl[sr * 64 + sc + 8 + j] = (float)v1[j];
      }
    }
    __syncthreads();
#pragma unroll 4
    for (int t = 0; t < 64; ++t) {
      f32x4 kv = *(const f32x4*)&Kl[t * 64 + d0];
      f32x4 vv = *(const f32x4*)&Vl[t * 64 + e0];
#pragma unroll
      for (int i = 0; i < 4; ++i) {
#pragma unroll
        for (int j = 0; j < 4; ++j) acc[i][j] += kv[i] * vv[j];
        ks[i] += kv[i];
      }
    }
  }
  float* outp = KVpart + ((size_t)split * 64 + bh) * 4096;
#pragma unroll
  for (int i = 0; i < 4; ++i)
#pragma unroll
    for (int j = 0; j < 4; ++j) outp[(d0 + i) * 64 + e0 + j] = acc[i][j];
  if ((tid & 15) == 0) {
    float* kp = KsumPart + ((size_t)split * 64 + bh) * 64;
#pragma unroll
    for (int i = 0; i < 4; ++i) kp[d0 + i] = ks[i];
  }
}

// ---- reduce partials -> KVt[bh][80][64] bf16 ([e][d]; row64=Ksum, 65..79=0)
__global__ __launch_bounds__(256) void kv_reduce(
    const float* __restrict__ KVpart, const float* __restrict__ KsumPart,
    bf16* __restrict__ KVt) {
  int bh = blockIdx.x;
  for (int idx = threadIdx.x; idx < 5120; idx += 256) {
    float s = 0.f;
    if (idx < 4096) {
      int e = idx >> 6, d = idx & 63;
      for (int sp = 0; sp < 16; ++sp)
        s += KVpart[((size_t)sp * 64 + bh) * 4096 + d * 64 + e];
    } else if (idx < 4160) {
      int d = idx - 4096;
      for (int sp = 0; sp < 16; ++sp)
        s += KsumPart[((size_t)sp * 64 + bh) * 64 + d];
    }
    KVt[(size_t)bh * 5120 + idx] = (bf16)s;
  }
}

// ---- attention: out = (Q @ KV) / (Q . Ksum + eps), in-place over Qp
__global__ __launch_bounds__(256) void attn(
    const bf16* __restrict__ KVt, bf16* __restrict__ QA) {
  __shared__ __align__(16) bf16 Bt[5120];
  const int bh = blockIdx.x, tc = blockIdx.y;
  const int b = bh >> 4, h = bh & 15;
  const int tid = threadIdx.x;
  const int m0 = b * 8192 + tc * 256;
#pragma unroll
  for (int i = 0; i < 3; ++i) {
    int e8 = tid + i * 256;
    if (e8 < 640) gl_lds16(KVt + (size_t)bh * 5120 + e8 * 8, &Bt[e8 * 8]);
  }
  const int wave = tid >> 6, lane = tid & 63;
  const int l16 = lane & 15, kg = lane >> 4;
  const int rowbase = m0 + wave * 64;
  __syncthreads();
  bf16x8 a[4][2];
#pragma unroll
  for (int fm = 0; fm < 4; ++fm)
#pragma unroll
    for (int kk = 0; kk < 2; ++kk)
      a[fm][kk] = *(const bf16x8*)(QA + (size_t)(rowbase + fm * 16 + l16) * 1024 +
                                   h * 64 + kk * 32 + kg * 8);
  f32x4 acc[4][4] = {};
  f32x4 accz[4] = {};
#pragma unroll
  for (int kk = 0; kk < 2; ++kk) {
    bf16x8 bz = *(const bf16x8*)&Bt[(64 + l16) * 64 + kk * 32 + kg * 8];
#pragma unroll
    for (int fn = 0; fn < 4; ++fn) {
      bf16x8 bb = *(const bf16x8*)&Bt[(fn * 16 + l16) * 64 + kk * 32 + kg * 8];
#pragma unroll
      for (int fm = 0; fm < 4; ++fm)
        acc[fm][fn] = __builtin_amdgcn_mfma_f32_16x16x32_bf16(
            a[fm][kk], bb, acc[fm][fn], 0, 0, 0);
    }
#pragma unroll
    for (int fm = 0; fm < 4; ++fm)
      accz[fm] = __builtin_amdgcn_mfma_f32_16x16x32_bf16(
          a[fm][kk], bz, accz[fm], 0, 0, 0);
  }
#pragma unroll
  for (int fm = 0; fm < 4; ++fm) {
#pragma unroll
    for (int i = 0; i < 4; ++i) {
      float z = __shfl(accz[fm][i], (lane & 48), 64) + EPS_Z_;
      float rz = 1.0f / z;
      int row = rowbase + fm * 16 + kg * 4 + i;
#pragma unroll
      for (int fn = 0; fn < 4; ++fn)
        QA[(size_t)row * 1024 + h * 64 + fn * 16 + l16] =
            (bf16)(acc[fm][fn][i] * rz);
    }
  }
}

extern "C" void kernel_launch(void* const* d_in, const int* in_sizes, int n_in,
                              void* d_out, int out_size, void* d_ws, size_t ws_size,
                              hipStream_t stream) {
  const float* query = (const float*)d_in[0];
  const float* key = (const float*)d_in[1];
  const float* value = (const float*)d_in[2];
  const float* Wq = (const float*)d_in[3];
  const float* bq = (const float*)d_in[4];
  const float* Wk = (const float*)d_in[5];
  const float* bk = (const float*)d_in[6];
  const float* Wv = (const float*)d_in[7];
  const float* bv = (const float*)d_in[8];
  const float* Wo = (const float*)d_in[9];
  const float* bo = (const float*)d_in[10];
  float* out = (float*)d_out;

  bf16* ws = (bf16*)d_ws;
  bf16* Wqb = ws;
  bf16* Wkb = ws + (1u << 20);
  bf16* Wvb = ws + (2u << 20);
  bf16* Wob = ws + (3u << 20);
  bf16* Qp = ws + (4u << 20);
  bf16* Kp = Qp + 33554432u;
  bf16* Vp = Kp + 33554432u;
  bf16* KVt = Vp + 33554432u;
  float* KVpart = (float*)(KVt + 327680u);
  float* KsumPart = KVpart + 16 * 64 * 4096;
  // Xc (bf16 cast of the current input, 64MB) lives in d_out: d_out is 128MB
  // fp32 and is only written by the final GEMM, after Xc's last use.
  bf16* Xc = (bf16*)d_out;

  const int NW = 1 << 20, NX = 33554432;
  cast_f2b<<<1024, 256, 0, stream>>>(Wq, Wqb, NW);
  cast_f2b<<<1024, 256, 0, stream>>>(Wk, Wkb, NW);
  cast_f2b<<<1024, 256, 0, stream>>>(Wv, Wvb, NW);
  cast_f2b<<<1024, 256, 0, stream>>>(Wo, Wob, NW);

  cast_f2b<<<2048, 256, 0, stream>>>(query, Xc, NX);
  gemm_bt<0><<<2048, 256, 0, stream>>>(Xc, Wqb, bq, Qp, nullptr);
  cast_f2b<<<2048, 256, 0, stream>>>(key, Xc, NX);
  gemm_bt<0><<<2048, 256, 0, stream>>>(Xc, Wkb, bk, Kp, nullptr);
  cast_f2b<<<2048, 256, 0, stream>>>(value, Xc, NX);
  gemm_bt<1><<<2048, 256, 0, stream>>>(Xc, Wvb, bv, Vp, nullptr);

  kv_partial<<<dim3(64, 16), 256, 0, stream>>>(Kp, Vp, KVpart, KsumPart);
  kv_reduce<<<64, 256, 0, stream>>>(KVpart, KsumPart, KVt);
  attn<<<dim3(64, 32), 256, 0, stream>>>(KVt, Qp);
  gemm_bt<2><<<2048, 256, 0, stream>>>(Qp, Wob, bo, nullptr, out);
}

// Round 3
// 557.386 us; speedup vs baseline: 1.3012x; 1.0992x over previous
//
#include <hip/hip_runtime.h>
#include <hip/hip_bf16.h>

// LinearAttention: B=4, T=8192, E=1024, H=16, D=64
//
// R2: GEMMs upgraded to 256x256 8-phase schedule (m201 template, plain HIP):
//   BM=BN=256, BK=64, 8 waves (2Mx4N), 128KB LDS double-buffered,
//   T2 XOR-swizzle (slot ^= row&7) both-sides, counted vmcnt(6) (T4),
//   setprio around 16-MFMA clusters (T5), bijective XCD swizzle (T1).
// LDS half-tiles are split by FRAGMENT GROUP (not contiguous rows):
//   A-half0 = rows read as fm0-3 (wm*128+0..63), A-half1 = fm4-7 rows
//   B-half0 = rows read as fn0-1 (wn*64+0..31),  B-half1 = fn2-3 rows
// so each phase's prefetch overwrites exactly the region whose reads
// completed one phase earlier. Stage order per tile t: X1=A03(t) @ t-2.ph2,
// X2=B23 @ t-2.ph3, X3=A47 @ t-2.ph4, X4=B01 @ t-1.ph1; vmcnt(6) at each
// ph4 guarantees tile t+1 fully landed at its ph1 (3 half-tiles in flight).

#define SCALE_ 0.125f
#define EPS_FM_ 1e-6f
#define EPS_Z_ 1e-8f

typedef __bf16 bf16;
typedef __attribute__((ext_vector_type(4))) __bf16 bf16x4;
typedef __attribute__((ext_vector_type(8))) __bf16 bf16x8;
typedef __attribute__((ext_vector_type(4))) float f32x4;

__device__ __forceinline__ void gl_lds16(const void* g, void* l) {
  __builtin_amdgcn_global_load_lds(
      (const __attribute__((address_space(1))) void*)g,
      (__attribute__((address_space(3))) void*)l, 16, 0, 0);
}

#define SBAR()                                  \
  do {                                          \
    __builtin_amdgcn_sched_barrier(0);          \
    asm volatile("s_barrier" ::: "memory");     \
    __builtin_amdgcn_sched_barrier(0);          \
  } while (0)

// ---- fp32 -> bf16 cast, grid-stride, vectorized
__global__ __launch_bounds__(256) void cast_f2b(const float* __restrict__ s,
                                                bf16* __restrict__ o, int n) {
  const int stride = gridDim.x * 256 * 4;
  for (int j = (blockIdx.x * 256 + threadIdx.x) * 4; j < n; j += stride) {
    float4 v = *(const float4*)(s + j);
    bf16x4 p = {(bf16)v.x, (bf16)v.y, (bf16)v.z, (bf16)v.w};
    *(bf16x4*)(o + j) = p;
  }
}

// ---- 256^2 8-phase GEMM: Out = f(A @ W^T + bias)
// OM 0: featuremap -> bf16; OM 1: plain -> bf16; OM 2: plain -> fp32
template <int OM>
__global__ __launch_bounds__(512, 2) void gemm8p(
    const bf16* __restrict__ A, const bf16* __restrict__ W,
    const float* __restrict__ bias, bf16* __restrict__ Pb,
    float* __restrict__ Pf) {
  __shared__ __align__(16) char lds[131072];
  const int tid = threadIdx.x;
  const int bid = blockIdx.x;
  // bijective XCD swizzle (gridDim.x % 8 == 0); n-tile fastest in-chunk
  const int wg = (bid & 7) * (gridDim.x >> 3) + (bid >> 3);
  const int m0 = (wg >> 2) * 256;
  const int n0 = (wg & 3) * 256;
  const int wave = tid >> 6, lane = tid & 63;
  const int wm = wave >> 2, wn = wave & 3;
  const int l16 = lane & 15, kg = lane >> 4;
  const int e = l16 & 7;
  const int sw0 = (kg ^ e) << 4;        // kk=0 swizzled 16B slot
  const int sw1 = ((4 | kg) ^ e) << 4;  // kk=1

  // staging constants: thread t covers LDS row lr=rd*64+(t>>3), slot t&7;
  // global col pre-swizzled so linear-LDS + swizzled-read is consistent.
  const int tr = tid >> 3;
  const int cslot = (tid & 7) ^ (tr & 7);
  const bf16* pA = A + (size_t)(m0 + tr) * 1024 + cslot * 8;
  const bf16* pB = W + (size_t)(n0 + ((tr >> 5) << 6) + (tr & 31)) * 1024 + cslot * 8;
  char* sA = lds;           // [0,64K): A buf0, buf1 (each 32K = half0|half1)
  char* sB = lds + 65536;   // [64K,128K): B buf0, buf1

  auto stgA = [&](int h, int kt, int bb) {  // h: 0=A03 rows, 1=A47 rows
    const bf16* g = pA + h * 65536 + kt * 64;
    char* d = sA + bb * 32768 + h * 16384 + tid * 16;
    gl_lds16(g, d);
    gl_lds16(g + 131072, d + 8192);  // rd=1: +128 global rows
  };
  auto stgB = [&](int h, int kt, int bb) {  // h: 0=B01 rows, 1=B23 rows
    const bf16* g = pB + h * 32768 + kt * 64;
    char* d = sB + bb * 32768 + h * 16384 + tid * 16;
    gl_lds16(g, d);
    gl_lds16(g + 131072, d + 8192);
  };

  const int aBase = wm * 8192 + l16 * 128;
  const int bBase = wn * 4096 + l16 * 128;
  auto ldA = [&](int bb, int h, int fmi, int kk) {
    return *(const bf16x8*)(sA + bb * 32768 + h * 16384 + aBase + fmi * 2048 +
                            (kk ? sw1 : sw0));
  };
  auto ldB = [&](int bb, int h, int fnj, int kk) {
    return *(const bf16x8*)(sB + bb * 32768 + h * 16384 + bBase + fnj * 2048 +
                            (kk ? sw1 : sw0));
  };

  f32x4 acc[8][4] = {};
  bf16x8 rA[4][2], rB01[2][2], rB23[2][2];
  const int NT = 16;  // K=1024 / BK=64

  // prologue: tile0 all 4 halves (X1..X4), tile1 X1..X3 -> 14 loads;
  // vmcnt(6) drains tile0 fully, keeps tile1's 3 halves in flight.
  stgA(0, 0, 0); stgB(1, 0, 0); stgA(1, 0, 0); stgB(0, 0, 0);
  stgA(0, 1, 1); stgB(1, 1, 1); stgA(1, 1, 1);
  asm volatile("s_waitcnt vmcnt(6)" ::: "memory");
  SBAR();

#pragma unroll 2
  for (int t = 0; t < NT; ++t) {
    const int c = t & 1;
    // ---- ph1: read A03+B01; stage X4(t+1)=B01 -> buf c^1
#pragma unroll
    for (int fmi = 0; fmi < 4; ++fmi) {
      rA[fmi][0] = ldA(c, 0, fmi, 0);
      rA[fmi][1] = ldA(c, 0, fmi, 1);
    }
#pragma unroll
    for (int fnj = 0; fnj < 2; ++fnj) {
      rB01[fnj][0] = ldB(c, 0, fnj, 0);
      rB01[fnj][1] = ldB(c, 0, fnj, 1);
    }
    if (t + 1 < NT) stgB(0, t + 1, c ^ 1);
    SBAR();
    __builtin_amdgcn_s_setprio(1);
#pragma unroll
    for (int fmi = 0; fmi < 4; ++fmi)
#pragma unroll
      for (int fnj = 0; fnj < 2; ++fnj)
#pragma unroll
        for (int kk = 0; kk < 2; ++kk)
          acc[fmi][fnj] = __builtin_amdgcn_mfma_f32_16x16x32_bf16(
              rA[fmi][kk], rB01[fnj][kk], acc[fmi][fnj], 0, 0, 0);
    __builtin_amdgcn_s_setprio(0);
    SBAR();
    // ---- ph2: read B23; stage X1(t+2)=A03 -> buf c
#pragma unroll
    for (int fnj = 0; fnj < 2; ++fnj) {
      rB23[fnj][0] = ldB(c, 1, fnj, 0);
      rB23[fnj][1] = ldB(c, 1, fnj, 1);
    }
    if (t + 2 < NT) stgA(0, t + 2, c);
    SBAR();
    __builtin_amdgcn_s_setprio(1);
#pragma unroll
    for (int fmi = 0; fmi < 4; ++fmi)
#pragma unroll
      for (int fnj = 0; fnj < 2; ++fnj)
#pragma unroll
        for (int kk = 0; kk < 2; ++kk)
          acc[fmi][2 + fnj] = __builtin_amdgcn_mfma_f32_16x16x32_bf16(
              rA[fmi][kk], rB23[fnj][kk], acc[fmi][2 + fnj], 0, 0, 0);
    __builtin_amdgcn_s_setprio(0);
    SBAR();
    // ---- ph3: read A47; stage X2(t+2)=B23 -> buf c
#pragma unroll
    for (int fmi = 0; fmi < 4; ++fmi) {
      rA[fmi][0] = ldA(c, 1, fmi, 0);
      rA[fmi][1] = ldA(c, 1, fmi, 1);
    }
    if (t + 2 < NT) stgB(1, t + 2, c);
    SBAR();
    __builtin_amdgcn_s_setprio(1);
#pragma unroll
    for (int fmi = 0; fmi < 4; ++fmi)
#pragma unroll
      for (int fnj = 0; fnj < 2; ++fnj)
#pragma unroll
        for (int kk = 0; kk < 2; ++kk)
          acc[4 + fmi][2 + fnj] = __builtin_amdgcn_mfma_f32_16x16x32_bf16(
              rA[fmi][kk], rB23[fnj][kk], acc[4 + fmi][2 + fnj], 0, 0, 0);
    __builtin_amdgcn_s_setprio(0);
    SBAR();
    // ---- ph4: stage X3(t+2)=A47 -> buf c; counted vmcnt; MFMA A47xB01
    if (t + 2 < NT) {
      stgA(1, t + 2, c);
      asm volatile("s_waitcnt vmcnt(6)" ::: "memory");
    } else {
      asm volatile("s_waitcnt vmcnt(0)" ::: "memory");
    }
    SBAR();
    __builtin_amdgcn_s_setprio(1);
#pragma unroll
    for (int fmi = 0; fmi < 4; ++fmi)
#pragma unroll
      for (int fnj = 0; fnj < 2; ++fnj)
#pragma unroll
        for (int kk = 0; kk < 2; ++kk)
          acc[4 + fmi][fnj] = __builtin_amdgcn_mfma_f32_16x16x32_bf16(
              rA[fmi][kk], rB01[fnj][kk], acc[4 + fmi][fnj], 0, 0, 0);
    __builtin_amdgcn_s_setprio(0);
    SBAR();
  }

  // epilogue
#pragma unroll
  for (int fn = 0; fn < 4; ++fn) {
    const int col = n0 + wn * 64 + fn * 16 + l16;
    const float bv = bias[col];
#pragma unroll
    for (int fm = 0; fm < 8; ++fm) {
      const int row = m0 + wm * 128 + fm * 16 + kg * 4;
#pragma unroll
      for (int i = 0; i < 4; ++i) {
        float v = acc[fm][fn][i] + bv;
        if (OM == 0) { v *= SCALE_; v = fmaxf(v, 0.f) + EPS_FM_; }
        if (OM < 2)
          Pb[(size_t)(row + i) * 1024 + col] = (bf16)v;
        else
          Pf[(size_t)(row + i) * 1024 + col] = v;
      }
    }
  }
}

// ---- KV partial: per (bh, split): KV[d][e] += K[t,d]*V[t,e], Ksum[d] += K[t,d]
__global__ __launch_bounds__(256) void kv_partial(
    const bf16* __restrict__ Kp, const bf16* __restrict__ Vp,
    float* __restrict__ KVpart, float* __restrict__ KsumPart) {
  __shared__ __align__(16) float Kl[64 * 64];
  __shared__ __align__(16) float Vl[64 * 64];
  const int bh = blockIdx.x, split = blockIdx.y;
  const int b = bh >> 4, h = bh & 15;
  const int tid = threadIdx.x;
  const int d0 = (tid >> 4) * 4, e0 = (tid & 15) * 4;
  float acc[4][4] = {};
  float ks[4] = {};
  const int sr = tid >> 2, sc = (tid & 3) * 16;
  for (int tc = 0; tc < 8; ++tc) {
    int t0 = split * 512 + tc * 64;
    __syncthreads();
    {
      size_t base = (size_t)(b * 8192 + t0 + sr) * 1024 + h * 64 + sc;
      bf16x8 k0 = *(const bf16x8*)(Kp + base);
      bf16x8 k1 = *(const bf16x8*)(Kp + base + 8);
      bf16x8 v0 = *(const bf16x8*)(Vp + base);
      bf16x8 v1 = *(const bf16x8*)(Vp + base + 8);
#pragma unroll
      for (int j = 0; j < 8; ++j) {
        Kl[sr * 64 + sc + j] = (float)k0[j];
        Kl[sr * 64 + sc + 8 + j] = (float)k1[j];
        Vl[sr * 64 + sc + j] = (float)v0[j];
        Vl[sr * 64 + sc + 8 + j] = (float)v1[j];
      }
    }
    __syncthreads();
#pragma unroll 4
    for (int t = 0; t < 64; ++t) {
      f32x4 kv = *(const f32x4*)&Kl[t * 64 + d0];
      f32x4 vv = *(const f32x4*)&Vl[t * 64 + e0];
#pragma unroll
      for (int i = 0; i < 4; ++i) {
#pragma unroll
        for (int j = 0; j < 4; ++j) acc[i][j] += kv[i] * vv[j];
        ks[i] += kv[i];
      }
    }
  }
  float* outp = KVpart + ((size_t)split * 64 + bh) * 4096;
#pragma unroll
  for (int i = 0; i < 4; ++i)
#pragma unroll
    for (int j = 0; j < 4; ++j) outp[(d0 + i) * 64 + e0 + j] = acc[i][j];
  if ((tid & 15) == 0) {
    float* kp = KsumPart + ((size_t)split * 64 + bh) * 64;
#pragma unroll
    for (int i = 0; i < 4; ++i) kp[d0 + i] = ks[i];
  }
}

// ---- reduce partials -> KVt[bh][80][64] bf16 ([e][d]; row64=Ksum, 65..79=0)
__global__ __launch_bounds__(256) void kv_reduce(
    const float* __restrict__ KVpart, const float* __restrict__ KsumPart,
    bf16* __restrict__ KVt) {
  int bh = blockIdx.x;
  for (int idx = threadIdx.x; idx < 5120; idx += 256) {
    float s = 0.f;
    if (idx < 4096) {
      int e = idx >> 6, d = idx & 63;
      for (int sp = 0; sp < 16; ++sp)
        s += KVpart[((size_t)sp * 64 + bh) * 4096 + d * 64 + e];
    } else if (idx < 4160) {
      int d = idx - 4096;
      for (int sp = 0; sp < 16; ++sp)
        s += KsumPart[((size_t)sp * 64 + bh) * 64 + d];
    }
    KVt[(size_t)bh * 5120 + idx] = (bf16)s;
  }
}

// ---- attention: out = (Q @ KV) / (Q . Ksum + eps), in-place over Qp
__global__ __launch_bounds__(256) void attn(
    const bf16* __restrict__ KVt, bf16* __restrict__ QA) {
  __shared__ __align__(16) bf16 Bt[5120];
  const int bh = blockIdx.x, tc = blockIdx.y;
  const int b = bh >> 4, h = bh & 15;
  const int tid = threadIdx.x;
  const int m0 = b * 8192 + tc * 256;
#pragma unroll
  for (int i = 0; i < 3; ++i) {
    int e8 = tid + i * 256;
    if (e8 < 640) gl_lds16(KVt + (size_t)bh * 5120 + e8 * 8, &Bt[e8 * 8]);
  }
  const int wave = tid >> 6, lane = tid & 63;
  const int l16 = lane & 15, kg = lane >> 4;
  const int rowbase = m0 + wave * 64;
  __syncthreads();
  bf16x8 a[4][2];
#pragma unroll
  for (int fm = 0; fm < 4; ++fm)
#pragma unroll
    for (int kk = 0; kk < 2; ++kk)
      a[fm][kk] = *(const bf16x8*)(QA + (size_t)(rowbase + fm * 16 + l16) * 1024 +
                                   h * 64 + kk * 32 + kg * 8);
  f32x4 acc[4][4] = {};
  f32x4 accz[4] = {};
#pragma unroll
  for (int kk = 0; kk < 2; ++kk) {
    bf16x8 bz = *(const bf16x8*)&Bt[(64 + l16) * 64 + kk * 32 + kg * 8];
#pragma unroll
    for (int fn = 0; fn < 4; ++fn) {
      bf16x8 bb = *(const bf16x8*)&Bt[(fn * 16 + l16) * 64 + kk * 32 + kg * 8];
#pragma unroll
      for (int fm = 0; fm < 4; ++fm)
        acc[fm][fn] = __builtin_amdgcn_mfma_f32_16x16x32_bf16(
            a[fm][kk], bb, acc[fm][fn], 0, 0, 0);
    }
#pragma unroll
    for (int fm = 0; fm < 4; ++fm)
      accz[fm] = __builtin_amdgcn_mfma_f32_16x16x32_bf16(
          a[fm][kk], bz, accz[fm], 0, 0, 0);
  }
#pragma unroll
  for (int fm = 0; fm < 4; ++fm) {
#pragma unroll
    for (int i = 0; i < 4; ++i) {
      float z = __shfl(accz[fm][i], (lane & 48), 64) + EPS_Z_;
      float rz = 1.0f / z;
      int row = rowbase + fm * 16 + kg * 4 + i;
#pragma unroll
      for (int fn = 0; fn < 4; ++fn)
        QA[(size_t)row * 1024 + h * 64 + fn * 16 + l16] =
            (bf16)(acc[fm][fn][i] * rz);
    }
  }
}

extern "C" void kernel_launch(void* const* d_in, const int* in_sizes, int n_in,
                              void* d_out, int out_size, void* d_ws, size_t ws_size,
                              hipStream_t stream) {
  const float* query = (const float*)d_in[0];
  const float* key = (const float*)d_in[1];
  const float* value = (const float*)d_in[2];
  const float* Wq = (const float*)d_in[3];
  const float* bq = (const float*)d_in[4];
  const float* Wk = (const float*)d_in[5];
  const float* bk = (const float*)d_in[6];
  const float* Wv = (const float*)d_in[7];
  const float* bv = (const float*)d_in[8];
  const float* Wo = (const float*)d_in[9];
  const float* bo = (const float*)d_in[10];
  float* out = (float*)d_out;

  bf16* ws = (bf16*)d_ws;
  bf16* Wqb = ws;
  bf16* Wkb = ws + (1u << 20);
  bf16* Wvb = ws + (2u << 20);
  bf16* Wob = ws + (3u << 20);
  bf16* Qp = ws + (4u << 20);
  bf16* Kp = Qp + 33554432u;
  bf16* Vp = Kp + 33554432u;
  bf16* KVt = Vp + 33554432u;
  float* KVpart = (float*)(KVt + 327680u);
  float* KsumPart = KVpart + 16 * 64 * 4096;
  // Xc (bf16 cast of the current input, 64MB) lives in d_out (128MB fp32),
  // dead before the final GEMM writes d_out.
  bf16* Xc = (bf16*)d_out;

  const int NW = 1 << 20, NX = 33554432;
  cast_f2b<<<1024, 256, 0, stream>>>(Wq, Wqb, NW);
  cast_f2b<<<1024, 256, 0, stream>>>(Wk, Wkb, NW);
  cast_f2b<<<1024, 256, 0, stream>>>(Wv, Wvb, NW);
  cast_f2b<<<1024, 256, 0, stream>>>(Wo, Wob, NW);

  cast_f2b<<<2048, 256, 0, stream>>>(query, Xc, NX);
  gemm8p<0><<<512, 512, 0, stream>>>(Xc, Wqb, bq, Qp, nullptr);
  cast_f2b<<<2048, 256, 0, stream>>>(key, Xc, NX);
  gemm8p<0><<<512, 512, 0, stream>>>(Xc, Wkb, bk, Kp, nullptr);
  cast_f2b<<<2048, 256, 0, stream>>>(value, Xc, NX);
  gemm8p<1><<<512, 512, 0, stream>>>(Xc, Wvb, bv, Vp, nullptr);

  kv_partial<<<dim3(64, 16), 256, 0, stream>>>(Kp, Vp, KVpart, KsumPart);
  kv_reduce<<<64, 256, 0, stream>>>(KVpart, KsumPart, KVt);
  attn<<<dim3(64, 32), 256, 0, stream>>>(KVt, Qp);
  gemm8p<2><<<512, 512, 0, stream>>>(Qp, Wob, bo, nullptr, out);
}

// Round 4
// 541.492 us; speedup vs baseline: 1.3394x; 1.0294x over previous
//
#include <hip/hip_runtime.h>
#include <hip/hip_bf16.h>

// LinearAttention: B=4, T=8192, E=1024, H=16, D=64
//
// R3: kv_partial -> MFMA with LDS-transposed K/V tiles (was 0% MfmaUtil VALU
//     outer product at 80us); attn I/O staged through swizzled LDS (was
//     2KB-stride scattered global frags). gemm8p/casts UNCHANGED from R2.
// KVpart/KsumPart moved into upper half of d_out (dead until final GEMM).

#define SCALE_ 0.125f
#define EPS_FM_ 1e-6f
#define EPS_Z_ 1e-8f

typedef __bf16 bf16;
typedef __attribute__((ext_vector_type(4))) __bf16 bf16x4;
typedef __attribute__((ext_vector_type(8))) __bf16 bf16x8;
typedef __attribute__((ext_vector_type(8))) unsigned short u16x8;
typedef __attribute__((ext_vector_type(4))) float f32x4;

__device__ __forceinline__ void gl_lds16(const void* g, void* l) {
  __builtin_amdgcn_global_load_lds(
      (const __attribute__((address_space(1))) void*)g,
      (__attribute__((address_space(3))) void*)l, 16, 0, 0);
}

#define SBAR()                                  \
  do {                                          \
    __builtin_amdgcn_sched_barrier(0);          \
    asm volatile("s_barrier" ::: "memory");     \
    __builtin_amdgcn_sched_barrier(0);          \
  } while (0)

// ---- weights fp32 -> bf16 (4 matrices, one dispatch)
__global__ __launch_bounds__(256) void cast_weights(
    const float* __restrict__ Wq, const float* __restrict__ Wk,
    const float* __restrict__ Wv, const float* __restrict__ Wo,
    bf16* __restrict__ out) {
  int which = blockIdx.y;
  int j = (blockIdx.x * 256 + threadIdx.x) * 4;
  const float* s = (which == 0) ? Wq : (which == 1) ? Wk : (which == 2) ? Wv : Wo;
  float4 v = *(const float4*)(s + j);
  bf16x4 p = {(bf16)v.x, (bf16)v.y, (bf16)v.z, (bf16)v.w};
  *(bf16x4*)(out + (size_t)which * (1u << 20) + j) = p;
}

// ---- fp32 -> bf16 cast, grid-stride
__global__ __launch_bounds__(256) void cast_f2b(const float* __restrict__ s,
                                                bf16* __restrict__ o, int n) {
  const int stride = gridDim.x * 256 * 4;
  for (int j = (blockIdx.x * 256 + threadIdx.x) * 4; j < n; j += stride) {
    float4 v = *(const float4*)(s + j);
    bf16x4 p = {(bf16)v.x, (bf16)v.y, (bf16)v.z, (bf16)v.w};
    *(bf16x4*)(o + j) = p;
  }
}

// ---- 256^2 8-phase GEMM (UNCHANGED from R2): Out = f(A @ W^T + bias)
template <int OM>
__global__ __launch_bounds__(512, 2) void gemm8p(
    const bf16* __restrict__ A, const bf16* __restrict__ W,
    const float* __restrict__ bias, bf16* __restrict__ Pb,
    float* __restrict__ Pf) {
  __shared__ __align__(16) char lds[131072];
  const int tid = threadIdx.x;
  const int bid = blockIdx.x;
  const int wg = (bid & 7) * (gridDim.x >> 3) + (bid >> 3);
  const int m0 = (wg >> 2) * 256;
  const int n0 = (wg & 3) * 256;
  const int wave = tid >> 6, lane = tid & 63;
  const int wm = wave >> 2, wn = wave & 3;
  const int l16 = lane & 15, kg = lane >> 4;
  const int e = l16 & 7;
  const int sw0 = (kg ^ e) << 4;
  const int sw1 = ((4 | kg) ^ e) << 4;

  const int tr = tid >> 3;
  const int cslot = (tid & 7) ^ (tr & 7);
  const bf16* pA = A + (size_t)(m0 + tr) * 1024 + cslot * 8;
  const bf16* pB = W + (size_t)(n0 + ((tr >> 5) << 6) + (tr & 31)) * 1024 + cslot * 8;
  char* sA = lds;
  char* sB = lds + 65536;

  auto stgA = [&](int h, int kt, int bb) {
    const bf16* g = pA + h * 65536 + kt * 64;
    char* d = sA + bb * 32768 + h * 16384 + tid * 16;
    gl_lds16(g, d);
    gl_lds16(g + 131072, d + 8192);
  };
  auto stgB = [&](int h, int kt, int bb) {
    const bf16* g = pB + h * 32768 + kt * 64;
    char* d = sB + bb * 32768 + h * 16384 + tid * 16;
    gl_lds16(g, d);
    gl_lds16(g + 131072, d + 8192);
  };

  const int aBase = wm * 8192 + l16 * 128;
  const int bBase = wn * 4096 + l16 * 128;
  auto ldA = [&](int bb, int h, int fmi, int kk) {
    return *(const bf16x8*)(sA + bb * 32768 + h * 16384 + aBase + fmi * 2048 +
                            (kk ? sw1 : sw0));
  };
  auto ldB = [&](int bb, int h, int fnj, int kk) {
    return *(const bf16x8*)(sB + bb * 32768 + h * 16384 + bBase + fnj * 2048 +
                            (kk ? sw1 : sw0));
  };

  f32x4 acc[8][4] = {};
  bf16x8 rA[4][2], rB01[2][2], rB23[2][2];
  const int NT = 16;

  stgA(0, 0, 0); stgB(1, 0, 0); stgA(1, 0, 0); stgB(0, 0, 0);
  stgA(0, 1, 1); stgB(1, 1, 1); stgA(1, 1, 1);
  asm volatile("s_waitcnt vmcnt(6)" ::: "memory");
  SBAR();

#pragma unroll 2
  for (int t = 0; t < NT; ++t) {
    const int c = t & 1;
#pragma unroll
    for (int fmi = 0; fmi < 4; ++fmi) {
      rA[fmi][0] = ldA(c, 0, fmi, 0);
      rA[fmi][1] = ldA(c, 0, fmi, 1);
    }
#pragma unroll
    for (int fnj = 0; fnj < 2; ++fnj) {
      rB01[fnj][0] = ldB(c, 0, fnj, 0);
      rB01[fnj][1] = ldB(c, 0, fnj, 1);
    }
    if (t + 1 < NT) stgB(0, t + 1, c ^ 1);
    SBAR();
    __builtin_amdgcn_s_setprio(1);
#pragma unroll
    for (int fmi = 0; fmi < 4; ++fmi)
#pragma unroll
      for (int fnj = 0; fnj < 2; ++fnj)
#pragma unroll
        for (int kk = 0; kk < 2; ++kk)
          acc[fmi][fnj] = __builtin_amdgcn_mfma_f32_16x16x32_bf16(
              rA[fmi][kk], rB01[fnj][kk], acc[fmi][fnj], 0, 0, 0);
    __builtin_amdgcn_s_setprio(0);
    SBAR();
#pragma unroll
    for (int fnj = 0; fnj < 2; ++fnj) {
      rB23[fnj][0] = ldB(c, 1, fnj, 0);
      rB23[fnj][1] = ldB(c, 1, fnj, 1);
    }
    if (t + 2 < NT) stgA(0, t + 2, c);
    SBAR();
    __builtin_amdgcn_s_setprio(1);
#pragma unroll
    for (int fmi = 0; fmi < 4; ++fmi)
#pragma unroll
      for (int fnj = 0; fnj < 2; ++fnj)
#pragma unroll
        for (int kk = 0; kk < 2; ++kk)
          acc[fmi][2 + fnj] = __builtin_amdgcn_mfma_f32_16x16x32_bf16(
              rA[fmi][kk], rB23[fnj][kk], acc[fmi][2 + fnj], 0, 0, 0);
    __builtin_amdgcn_s_setprio(0);
    SBAR();
#pragma unroll
    for (int fmi = 0; fmi < 4; ++fmi) {
      rA[fmi][0] = ldA(c, 1, fmi, 0);
      rA[fmi][1] = ldA(c, 1, fmi, 1);
    }
    if (t + 2 < NT) stgB(1, t + 2, c);
    SBAR();
    __builtin_amdgcn_s_setprio(1);
#pragma unroll
    for (int fmi = 0; fmi < 4; ++fmi)
#pragma unroll
      for (int fnj = 0; fnj < 2; ++fnj)
#pragma unroll
        for (int kk = 0; kk < 2; ++kk)
          acc[4 + fmi][2 + fnj] = __builtin_amdgcn_mfma_f32_16x16x32_bf16(
              rA[fmi][kk], rB23[fnj][kk], acc[4 + fmi][2 + fnj], 0, 0, 0);
    __builtin_amdgcn_s_setprio(0);
    SBAR();
    if (t + 2 < NT) {
      stgA(1, t + 2, c);
      asm volatile("s_waitcnt vmcnt(6)" ::: "memory");
    } else {
      asm volatile("s_waitcnt vmcnt(0)" ::: "memory");
    }
    SBAR();
    __builtin_amdgcn_s_setprio(1);
#pragma unroll
    for (int fmi = 0; fmi < 4; ++fmi)
#pragma unroll
      for (int fnj = 0; fnj < 2; ++fnj)
#pragma unroll
        for (int kk = 0; kk < 2; ++kk)
          acc[4 + fmi][fnj] = __builtin_amdgcn_mfma_f32_16x16x32_bf16(
              rA[fmi][kk], rB01[fnj][kk], acc[4 + fmi][fnj], 0, 0, 0);
    __builtin_amdgcn_s_setprio(0);
    SBAR();
  }

#pragma unroll
  for (int fn = 0; fn < 4; ++fn) {
    const int col = n0 + wn * 64 + fn * 16 + l16;
    const float bv = bias[col];
#pragma unroll
    for (int fm = 0; fm < 8; ++fm) {
      const int row = m0 + wm * 128 + fm * 16 + kg * 4;
#pragma unroll
      for (int i = 0; i < 4; ++i) {
        float v = acc[fm][fn][i] + bv;
        if (OM == 0) { v *= SCALE_; v = fmaxf(v, 0.f) + EPS_FM_; }
        if (OM < 2)
          Pb[(size_t)(row + i) * 1024 + col] = (bf16)v;
        else
          Pf[(size_t)(row + i) * 1024 + col] = v;
      }
    }
  }
}

// ---- KV via MFMA: per (bh, split of 256 rows):
//   KVpart[d][e] = sum_t K[t][d] V[t][e];  KsumPart[d] = sum_t K[t][d]
// K,V tiles staged TRANSPOSED in LDS: Xt[d][t] (row 512B, 32 granules of 16B),
// granule swizzle g ^= (d&7)^((d>>3)&7) -> <=2-way conflicts on write & read.
__global__ __launch_bounds__(256) void kv_mfma(
    const bf16* __restrict__ Kp, const bf16* __restrict__ Vp,
    float* __restrict__ KVpart, float* __restrict__ KsumPart) {
  __shared__ __align__(16) char lds[65536];
  char* Kt = lds;
  char* Vt = lds + 32768;
  const int bh = blockIdx.x, split = blockIdx.y;
  const int b = bh >> 4, h = bh & 15;
  const int tid = threadIdx.x;
  const int p = tid >> 3, c = tid & 7;
  const size_t gbase = (size_t)(b * 8192 + split * 256) * 1024 + h * 64 + c * 8;

#pragma unroll
  for (int i = 0; i < 4; ++i) {
    const int t = i * 64 + p * 2;
    const size_t ga = gbase + (size_t)t * 1024;
    bf16x8 k0 = *(const bf16x8*)(Kp + ga);
    bf16x8 k1 = *(const bf16x8*)(Kp + ga + 1024);
    bf16x8 v0 = *(const bf16x8*)(Vp + ga);
    bf16x8 v1 = *(const bf16x8*)(Vp + ga + 1024);
    u16x8 a0 = __builtin_bit_cast(u16x8, k0);
    u16x8 a1 = __builtin_bit_cast(u16x8, k1);
    u16x8 b0 = __builtin_bit_cast(u16x8, v0);
    u16x8 b1 = __builtin_bit_cast(u16x8, v1);
    const int gt = t >> 3, tl = (t & 7) * 2;
#pragma unroll
    for (int j = 0; j < 8; ++j) {
      const int d = c * 8 + j;
      const int off = d * 512 + ((gt ^ (d & 7) ^ c) << 4) + tl;
      *(unsigned int*)(Kt + off) = (unsigned int)a0[j] | ((unsigned int)a1[j] << 16);
      *(unsigned int*)(Vt + off) = (unsigned int)b0[j] | ((unsigned int)b1[j] << 16);
    }
  }
  __syncthreads();

  const int wave = tid >> 6, lane = tid & 63;
  const int wd = wave >> 1, we = wave & 1;
  const int l16 = lane & 15, kg = lane >> 4;
  f32x4 acc[2][2] = {};
  f32x4 accz[2] = {};
  const bf16x8 ones = {1.f, 1.f, 1.f, 1.f, 1.f, 1.f, 1.f, 1.f};

#pragma unroll
  for (int ks = 0; ks < 8; ++ks) {
    const int g = ks * 4 + kg;
    bf16x8 af[2], bf_[2];
#pragma unroll
    for (int f = 0; f < 2; ++f) {
      const int d = wd * 32 + f * 16 + l16;
      af[f] = *(const bf16x8*)(Kt + d * 512 + ((g ^ (d & 7) ^ ((d >> 3) & 7)) << 4));
      const int ee = we * 32 + f * 16 + l16;
      bf_[f] = *(const bf16x8*)(Vt + ee * 512 + ((g ^ (ee & 7) ^ ((ee >> 3) & 7)) << 4));
    }
#pragma unroll
    for (int fa = 0; fa < 2; ++fa) {
#pragma unroll
      for (int fb = 0; fb < 2; ++fb)
        acc[fa][fb] = __builtin_amdgcn_mfma_f32_16x16x32_bf16(
            af[fa], bf_[fb], acc[fa][fb], 0, 0, 0);
      if (we == 0)
        accz[fa] = __builtin_amdgcn_mfma_f32_16x16x32_bf16(
            af[fa], ones, accz[fa], 0, 0, 0);
    }
  }

  float* outp = KVpart + ((size_t)split * 64 + bh) * 4096;
#pragma unroll
  for (int fa = 0; fa < 2; ++fa)
#pragma unroll
    for (int i = 0; i < 4; ++i) {
      const int d = wd * 32 + fa * 16 + kg * 4 + i;
#pragma unroll
      for (int fb = 0; fb < 2; ++fb)
        outp[d * 64 + we * 32 + fb * 16 + l16] = acc[fa][fb][i];
      if (we == 0 && l16 == 0)
        KsumPart[((size_t)split * 64 + bh) * 64 + d] = accz[fa][i];
    }
}

// ---- reduce 32 split-partials -> KVt[bh][80][64] bf16 ([e][d]; row64=Ksum)
__global__ __launch_bounds__(256) void kv_reduce(
    const float* __restrict__ KVpart, const float* __restrict__ KsumPart,
    bf16* __restrict__ KVt) {
  int bh = blockIdx.x;
  for (int idx = threadIdx.x; idx < 5120; idx += 256) {
    float s = 0.f;
    if (idx < 4096) {
      int e = idx >> 6, d = idx & 63;
      for (int sp = 0; sp < 32; ++sp)
        s += KVpart[((size_t)sp * 64 + bh) * 4096 + d * 64 + e];
    } else if (idx < 4160) {
      int d = idx - 4096;
      for (int sp = 0; sp < 32; ++sp)
        s += KsumPart[((size_t)sp * 64 + bh) * 64 + d];
    }
    KVt[(size_t)bh * 5120 + idx] = (bf16)s;
  }
}

// ---- attention: out = (Q @ KV) / (Q . Ksum + eps), in-place over Qp.
// Q tile + KVt staged via gl_lds w/ pre-swizzled global source; frag reads
// swizzled; output bounced through LDS for coalesced 16B stores.
__global__ __launch_bounds__(256) void attn(
    const bf16* __restrict__ KVt, bf16* __restrict__ QA) {
  __shared__ __align__(16) char lds[43008];  // Qt [256][64] 32KB + Bt [80][64] 10.25KB
  char* Qt = lds;
  char* Bt = lds + 32768;
  const int bh = blockIdx.x, tc = blockIdx.y;
  const int b = bh >> 4, h = bh & 15;
  const int tid = threadIdx.x;
  const int m0 = b * 8192 + tc * 256;

  // stage Q tile: granule gidx: row=gidx>>3, g=gidx&7; global src pre-swizzled
#pragma unroll
  for (int i = 0; i < 8; ++i) {
    const int gidx = i * 256 + tid;
    const int row = gidx >> 3, g = gidx & 7;
    const int gsrc = g ^ (row & 7);
    gl_lds16(QA + (size_t)(m0 + row) * 1024 + h * 64 + gsrc * 8, Qt + gidx * 16);
  }
#pragma unroll
  for (int i = 0; i < 3; ++i) {
    const int gidx = i * 256 + tid;
    if (gidx < 640) {
      const int row = gidx >> 3, g = gidx & 7;
      const int gsrc = g ^ (row & 7);
      gl_lds16(KVt + (size_t)bh * 5120 + row * 64 + gsrc * 8, Bt + gidx * 16);
    }
  }
  __syncthreads();

  const int wave = tid >> 6, lane = tid & 63;
  const int l16 = lane & 15, kg = lane >> 4;
  bf16x8 a[4][2];
#pragma unroll
  for (int fm = 0; fm < 4; ++fm)
#pragma unroll
    for (int kk = 0; kk < 2; ++kk) {
      const int row = wave * 64 + fm * 16 + l16;
      const int g = kk * 4 + kg;
      a[fm][kk] = *(const bf16x8*)(Qt + row * 128 + ((g ^ (row & 7)) << 4));
    }
  f32x4 acc[4][4] = {};
  f32x4 accz[4] = {};
#pragma unroll
  for (int kk = 0; kk < 2; ++kk) {
    const int g = kk * 4 + kg;
    const int zr = 64 + l16;
    bf16x8 bz = *(const bf16x8*)(Bt + zr * 128 + ((g ^ (zr & 7)) << 4));
#pragma unroll
    for (int fn = 0; fn < 4; ++fn) {
      const int br = fn * 16 + l16;
      bf16x8 bb = *(const bf16x8*)(Bt + br * 128 + ((g ^ (br & 7)) << 4));
#pragma unroll
      for (int fm = 0; fm < 4; ++fm)
        acc[fm][fn] = __builtin_amdgcn_mfma_f32_16x16x32_bf16(
            a[fm][kk], bb, acc[fm][fn], 0, 0, 0);
    }
#pragma unroll
    for (int fm = 0; fm < 4; ++fm)
      accz[fm] = __builtin_amdgcn_mfma_f32_16x16x32_bf16(
          a[fm][kk], bz, accz[fm], 0, 0, 0);
  }
  __syncthreads();  // all Q-frag reads done; Qt reused as output buffer

#pragma unroll
  for (int fm = 0; fm < 4; ++fm)
#pragma unroll
    for (int i = 0; i < 4; ++i) {
      const float z = __shfl(accz[fm][i], (lane & 48), 64) + EPS_Z_;
      const float rz = 1.0f / z;
      const int row = wave * 64 + fm * 16 + kg * 4 + i;
#pragma unroll
      for (int fn = 0; fn < 4; ++fn) {
        const int col = fn * 16 + l16;
        const int gc = col >> 3;
        bf16 v = (bf16)(acc[fm][fn][i] * rz);
        *(unsigned short*)(Qt + row * 128 + ((gc ^ (row & 7)) << 4) + (col & 7) * 2) =
            __builtin_bit_cast(unsigned short, v);
      }
    }
  __syncthreads();

#pragma unroll
  for (int i = 0; i < 8; ++i) {
    const int gidx = i * 256 + tid;
    const int row = gidx >> 3, g = gidx & 7;
    bf16x8 v = *(const bf16x8*)(Qt + row * 128 + ((g ^ (row & 7)) << 4));
    *(bf16x8*)(QA + (size_t)(m0 + row) * 1024 + h * 64 + g * 8) = v;
  }
}

extern "C" void kernel_launch(void* const* d_in, const int* in_sizes, int n_in,
                              void* d_out, int out_size, void* d_ws, size_t ws_size,
                              hipStream_t stream) {
  const float* query = (const float*)d_in[0];
  const float* key = (const float*)d_in[1];
  const float* value = (const float*)d_in[2];
  const float* Wq = (const float*)d_in[3];
  const float* bq = (const float*)d_in[4];
  const float* Wk = (const float*)d_in[5];
  const float* bk = (const float*)d_in[6];
  const float* Wv = (const float*)d_in[7];
  const float* bv = (const float*)d_in[8];
  const float* Wo = (const float*)d_in[9];
  const float* bo = (const float*)d_in[10];
  float* out = (float*)d_out;

  bf16* ws = (bf16*)d_ws;
  bf16* Wqb = ws;
  bf16* Wkb = ws + (1u << 20);
  bf16* Wvb = ws + (2u << 20);
  bf16* Wob = ws + (3u << 20);
  bf16* Qp = ws + (4u << 20);
  bf16* Kp = Qp + 33554432u;
  bf16* Vp = Kp + 33554432u;
  bf16* KVt = Vp + 33554432u;
  // d_out (128MiB fp32) as scratch: [0,64MiB) = Xc bf16 cast of current input;
  // [64,96MiB) = KVpart fp32; [96,96.5MiB) = KsumPart. All dead before the
  // final GEMM overwrites d_out.
  bf16* Xc = (bf16*)d_out;
  float* KVpart = (float*)d_out + 16777216u;
  float* KsumPart = KVpart + 8388608u;

  const int NW = 1 << 20, NX = 33554432;
  cast_weights<<<dim3(1024, 4), 256, 0, stream>>>(Wq, Wk, Wv, Wo, Wqb);

  cast_f2b<<<2048, 256, 0, stream>>>(query, Xc, NX);
  gemm8p<0><<<512, 512, 0, stream>>>(Xc, Wqb, bq, Qp, nullptr);
  cast_f2b<<<2048, 256, 0, stream>>>(key, Xc, NX);
  gemm8p<0><<<512, 512, 0, stream>>>(Xc, Wkb, bk, Kp, nullptr);
  cast_f2b<<<2048, 256, 0, stream>>>(value, Xc, NX);
  gemm8p<1><<<512, 512, 0, stream>>>(Xc, Wvb, bv, Vp, nullptr);

  kv_mfma<<<dim3(64, 32), 256, 0, stream>>>(Kp, Vp, KVpart, KsumPart);
  kv_reduce<<<64, 256, 0, stream>>>(KVpart, KsumPart, KVt);
  attn<<<dim3(64, 32), 256, 0, stream>>>(KVt, Qp);
  gemm8p<2><<<512, 512, 0, stream>>>(Qp, Wob, bo, nullptr, out);
}